// Round 1
// baseline (322.733 us; speedup 1.0000x reference)
//
#include <hip/hip_runtime.h>
#include <hip/hip_bf16.h>
#include <stdint.h>
#include <stddef.h>

#define DIM 1024
#define SEQ 2048
#define KF 24
#define HALFLEN 1024
#define MROWS 8192   // 4*2048 flattened (b,t)

using f32x4  = __attribute__((ext_vector_type(4))) float;
using bf16x8 = __attribute__((ext_vector_type(8))) short;

__device__ __forceinline__ float bf2f(unsigned short u){
  union { unsigned int i; float f; } v; v.i = ((unsigned int)u) << 16; return v.f;
}
__device__ __forceinline__ unsigned short f2bf(float f){
  union { float f; unsigned int i; } v; v.f = f;
  unsigned int r = v.i + 0x7FFFu + ((v.i >> 16) & 1u);  // RNE
  return (unsigned short)(r >> 16);
}
__device__ __forceinline__ void gload_lds16(const void* g, void* l){
  __builtin_amdgcn_global_load_lds(
      (const __attribute__((address_space(1))) unsigned int*)g,
      (__attribute__((address_space(3))) unsigned int*)l, 16, 0, 0);
}

// ---------------- prep: x fp32 -> bf16 ----------------
__global__ void k_cvt_x(const float* __restrict__ x, unsigned short* __restrict__ xb){
  int i = blockIdx.x * 256 + threadIdx.x;            // each thread 4 elems
  const float4* x4 = (const float4*)x;
  float4 v = x4[i];
  ushort4 o;
  o.x = f2bf(v.x); o.y = f2bf(v.y); o.z = f2bf(v.z); o.w = f2bf(v.w);
  *(ushort4*)(xb + (size_t)i * 4) = o;
}

// ---------------- prep: M_inputs transpose -> bf16 (B^T, [d][e]) ----------------
__global__ void k_tr_M(const float* __restrict__ Mi, unsigned short* __restrict__ MbT){
  __shared__ float tile[32][33];
  int e0 = blockIdx.y * 32, d0 = blockIdx.x * 32;
  int tx = threadIdx.x, ty = threadIdx.y;            // block (32,8)
  #pragma unroll
  for (int r = 0; r < 32; r += 8)
    tile[ty + r][tx] = Mi[(size_t)(e0 + ty + r) * DIM + d0 + tx];
  __syncthreads();
  #pragma unroll
  for (int r = 0; r < 32; r += 8)
    MbT[(size_t)(d0 + ty + r) * DIM + e0 + tx] = f2bf(tile[tx][ty + r]);
}

// ---------------- prep: pe[r][d] = 2 * (filters @ M_filters)[2r][d], bf16 ----------------
__global__ void k_pe(const float* __restrict__ filters, const float* __restrict__ Mf,
                     unsigned short* __restrict__ pe){
  int d = blockIdx.x * 256 + threadIdx.x;            // 0..1023
  int r = blockIdx.y;                                // 0..1023
  float acc = 0.f;
  #pragma unroll
  for (int k = 0; k < KF; ++k)
    acc += filters[(size_t)(2 * r) * KF + k] * Mf[(size_t)k * DIM + d];
  pe[(size_t)r * DIM + d] = f2bf(2.f * acc);
}

// ---------------- GEMM: x_proj = x @ M_inputs (bf16 MFMA, bf16 out) ----------------
// A: [8192][1024] bf16 row-major. Bt: [1024 n][1024 k] bf16 (= M_inputs^T). C: [8192][1024] bf16.
#define BM 128
#define BN 128
#define BKK 64
__global__ void k_gemm(const unsigned short* __restrict__ A,
                       const unsigned short* __restrict__ Bt,
                       unsigned short* __restrict__ C){
  __shared__ unsigned short As[BM * BKK];   // 16 KB, XOR-swizzled (unit16B ^= row&7)
  __shared__ unsigned short Bs[BN * BKK];   // 16 KB
  int tid  = threadIdx.x;
  int lane = tid & 63, wave = tid >> 6;
  int wm = wave >> 1, wn = wave & 1;
  int trow0 = blockIdx.x * BM;
  int ncol0 = blockIdx.y * BN;

  f32x4 acc[4][4] = {};

  for (int kt = 0; kt < 1024 / BKK; ++kt){
    __syncthreads();   // previous tile's reads done
    #pragma unroll
    for (int g = 0; g < 4; ++g){
      int c  = wave * 4 + g;              // chunk 0..15, 1KB each
      int mr = c * 8 + (lane >> 3);       // tile row this lane stages
      int u  = lane & 7;                  // physical 16B unit within row
      int su = u ^ (mr & 7);              // source (logical) unit
      const unsigned short* srcA = A + (size_t)(trow0 + mr) * 1024 + kt * BKK + su * 8;
      gload_lds16(srcA, (char*)As + c * 1024);
      const unsigned short* srcB = Bt + (size_t)(ncol0 + mr) * 1024 + kt * BKK + su * 8;
      gload_lds16(srcB, (char*)Bs + c * 1024);
    }
    __syncthreads();   // vmcnt(0) drain + barrier

    bf16x8 af[4][2], bfr[4][2];
    #pragma unroll
    for (int mi = 0; mi < 4; ++mi){
      int row = wm * 64 + mi * 16 + (lane & 15);
      #pragma unroll
      for (int ks = 0; ks < 2; ++ks){
        int u = ((lane >> 4) + 4 * ks) ^ (row & 7);
        af[mi][ks] = *(const bf16x8*)((const char*)As + row * 128 + u * 16);
      }
    }
    #pragma unroll
    for (int ni = 0; ni < 4; ++ni){
      int row = wn * 64 + ni * 16 + (lane & 15);
      #pragma unroll
      for (int ks = 0; ks < 2; ++ks){
        int u = ((lane >> 4) + 4 * ks) ^ (row & 7);
        bfr[ni][ks] = *(const bf16x8*)((const char*)Bs + row * 128 + u * 16);
      }
    }
    #pragma unroll
    for (int mi = 0; mi < 4; ++mi)
      #pragma unroll
      for (int ni = 0; ni < 4; ++ni)
        #pragma unroll
        for (int ks = 0; ks < 2; ++ks)
          acc[mi][ni] = __builtin_amdgcn_mfma_f32_16x16x32_bf16(
              af[mi][ks], bfr[ni][ks], acc[mi][ni], 0, 0, 0);
  }

  // epilogue: C[row = (lane>>4)*4+reg][col = lane&15] per 16x16 frag
  #pragma unroll
  for (int mi = 0; mi < 4; ++mi)
    #pragma unroll
    for (int ni = 0; ni < 4; ++ni){
      int col = ncol0 + wn * 64 + ni * 16 + (lane & 15);
      #pragma unroll
      for (int reg = 0; reg < 4; ++reg){
        int row = trow0 + wm * 64 + mi * 16 + (lane >> 4) * 4 + reg;
        C[(size_t)row * 1024 + col] = f2bf(acc[mi][ni][reg]);
      }
    }
}

// ---------------- depthwise causal conv (half-rate, even-lag filter) ----------------
// out[b, 2m+p, d] = sum_{r<=m} pe[r,d] * xp[b, 2(m-r)+p, d]
#define MV 32
__global__ void k_conv(const unsigned short* __restrict__ xp,  // [8192][1024] bf16
                       const unsigned short* __restrict__ pe,  // [1024][1024] bf16
                       float* __restrict__ out){               // [4][2048][1024] f32
  int d  = blockIdx.x * 256 + threadIdx.x;   // 0..1023, lane = channel
  int m0 = blockIdx.y * MV;                  // 0..992
  int bp = blockIdx.z;                       // 0..7
  int b = bp >> 1, p = bp & 1;
  const unsigned short* xrow  = xp + ((size_t)b * SEQ + p) * DIM + d;  // + j*2048 elems
  const unsigned short* perow = pe + d;                                // + r*1024 elems

  float acc[MV];
  #pragma unroll
  for (int m = 0; m < MV; ++m) acc[m] = 0.f;

  int nmain = m0 >> 4;   // chunks with fully in-range x window
  for (int ch = 0; ch < nmain; ++ch){
    int r0 = ch * 16;
    int jbase = m0 - r0 - 15;
    float xw[47], pv[16];
    #pragma unroll
    for (int i = 0; i < 47; ++i) xw[i] = bf2f(xrow[(size_t)(jbase + i) * 2048]);
    #pragma unroll
    for (int i = 0; i < 16; ++i) pv[i] = bf2f(perow[(size_t)(r0 + i) * 1024]);
    #pragma unroll
    for (int i = 0; i < 16; ++i)
      #pragma unroll
      for (int m = 0; m < MV; ++m)
        acc[m] += pv[i] * xw[m + 15 - i];
  }
  // two tail chunks (r0 = m0, m0+16): x window hits j<0 -> zero (enforces r<=m)
  #pragma unroll
  for (int tch = 0; tch < 2; ++tch){
    int r0 = m0 + tch * 16;
    int jbase = m0 - r0 - 15;
    float xw[47], pv[16];
    #pragma unroll
    for (int i = 0; i < 47; ++i){
      int j = jbase + i;
      xw[i] = (j >= 0) ? bf2f(xrow[(size_t)j * 2048]) : 0.f;
    }
    #pragma unroll
    for (int i = 0; i < 16; ++i) pv[i] = bf2f(perow[(size_t)(r0 + i) * 1024]);
    #pragma unroll
    for (int i = 0; i < 16; ++i)
      #pragma unroll
      for (int m = 0; m < MV; ++m)
        acc[m] += pv[i] * xw[m + 15 - i];
  }

  float* obase = out + ((size_t)b * SEQ + p) * DIM + d;   // + m*2048 elems
  #pragma unroll
  for (int m = 0; m < MV; ++m)
    obase[(size_t)(m0 + m) * 2048] = acc[m];
}

extern "C" void kernel_launch(void* const* d_in, const int* in_sizes, int n_in,
                              void* d_out, int out_size, void* d_ws, size_t ws_size,
                              hipStream_t stream){
  const float* x       = (const float*)d_in[0];
  const float* filters = (const float*)d_in[1];
  const float* Mi      = (const float*)d_in[2];
  const float* Mf      = (const float*)d_in[3];
  // d_in[4] = input_pos (unused)

  char* ws = (char*)d_ws;
  unsigned short* Xb  = (unsigned short*)(ws);                              // 16 MB
  unsigned short* XPb = (unsigned short*)(ws + (size_t)16 * 1024 * 1024);   // 16 MB
  unsigned short* MbT = (unsigned short*)(ws + (size_t)32 * 1024 * 1024);   //  2 MB
  unsigned short* pe  = (unsigned short*)(ws + (size_t)34 * 1024 * 1024);   //  2 MB
  float* out = (float*)d_out;

  hipLaunchKernelGGL(k_cvt_x, dim3(8192), dim3(256), 0, stream, x, Xb);
  hipLaunchKernelGGL(k_tr_M,  dim3(32, 32), dim3(32, 8), 0, stream, Mi, MbT);
  hipLaunchKernelGGL(k_pe,    dim3(4, 1024), dim3(256), 0, stream, filters, Mf, pe);
  hipLaunchKernelGGL(k_gemm,  dim3(64, 8), dim3(256), 0, stream, Xb, MbT, XPb);
  hipLaunchKernelGGL(k_conv,  dim3(4, 32, 8), dim3(256), 0, stream, XPb, pe, out);
}